// Round 6
// baseline (114.543 us; speedup 1.0000x reference)
//
#include <hip/hip_runtime.h>

// DistNet: out[n] = sigmoid((min_p ||x_n - p||^2 + alpha) / beta)
// beta = softplus(beta_raw), alpha = -beta*ln(1000)
// x: [65536,128] f32, points: [2048,128] f32, beta_raw: [1] f32, out: [65536] f32
//
// R12: MEASUREMENT ROUND + pipeline polish. Every structure R6-R11 lands at
// m ~= 34-42 us (vs 12.5 us floor) and main is never visible in top-5
// (each dispatch < the 43 us poison fill). So: launch main TWICE
// (idempotent) -> wall = overhead(62+-3, calibrated from R2/R3) + 2*m,
// giving m at +-1.5 us resolution. Kernel = R7 topology (best measured:
// 512 blocks x 256 thr, wave pair owns 64 rows, halves split the 128
// point-tiles 64 each -> only 2 B-streams per block) + R10's pipeline
// discipline (depth-4 named-buffer prefetch, #pragma unroll 1, branch-free
// steady state) which R7 never had (it was depth-2 with per-iter ifs).

#define NROWS 65536
#define NPTS  2048
#define DIMS  128
#define LOG1000F 6.9077542789816375f

typedef __attribute__((ext_vector_type(8))) int i32x8;
typedef __attribute__((ext_vector_type(4))) float f32x4;

union AFrag { int d[8]; i32x8 v; };
union BFrag { uint4 u4[2]; i32x8 v; };

// --- pre-kernel: points f32 -> fp8 e4m3, PRE-SWIZZLED fragment order --------
// 16B unit u = (T*2+c)*64 + q*16 + m  holds point p = T*16+m, features
// k in [q*32+c*16, q*32+c*16+16). Main kernel B-load for tile T is then
// unit[(T*2+c)*64 + lane], i.e. two contiguous 1KB dwordx4 loads.
// Also writes ||p||^2.
__global__ __launch_bounds__(256) void prep_points_kernel(
    const float* __restrict__ pts, unsigned char* __restrict__ ptsf8,
    float* __restrict__ pnorm)
{
    int tid  = threadIdx.x;
    int lane = tid & 63;
    int w    = tid >> 6;
    int pt   = blockIdx.x * 4 + w;            // one wave per point
    const float2 v = *reinterpret_cast<const float2*>(
        pts + (size_t)pt * DIMS + lane * 2);  // features 2*lane, 2*lane+1
    int pk = __builtin_amdgcn_cvt_pk_fp8_f32(v.x, v.y, 0, false);
    int T  = pt >> 4, pm = pt & 15;
    int q  = lane >> 4;                       // (2*lane)>>5
    int c  = (lane >> 3) & 1;                 // ((2*lane)>>4)&1
    int j  = (lane & 7) * 2;                  // (2*lane)&15
    size_t dst = (size_t)((T * 2 + c) * 64 + q * 16 + pm) * 16 + j;
    *reinterpret_cast<unsigned short*>(ptsf8 + dst) =
        (unsigned short)(pk & 0xFFFF);
    float ss = v.x * v.x + v.y * v.y;
    ss += __shfl_xor(ss, 1, 64);
    ss += __shfl_xor(ss, 2, 64);
    ss += __shfl_xor(ss, 4, 64);
    ss += __shfl_xor(ss, 8, 64);
    ss += __shfl_xor(ss, 16, 64);
    ss += __shfl_xor(ss, 32, 64);
    if (lane == 0) pnorm[pt] = ss;
}

// --- main kernel ------------------------------------------------------------
// grid: NROWS/128 = 512 blocks x 256 threads (4 waves, 2 per CU).
// Wave pair (pairw) owns 64 rows; half=0 wave does point-tiles 0..63,
// half=1 wave does 64..127. No barriers in the main loop.
__global__ __launch_bounds__(256, 2) void distnet_main_kernel(
    const float* __restrict__ x, const unsigned char* __restrict__ ptsf8,
    const float* __restrict__ pnorm, const float* __restrict__ beta_raw,
    float* __restrict__ out)
{
    __shared__ __align__(16) float s_pn[NPTS];   // 8 KB: -0.5*||p||^2
    __shared__ float s_red[2][128];              // per-half partial max
    __shared__ float s_xn[128];                  // ||x||^2 per block row

    int tid = threadIdx.x;
    // stage -0.5*||p||^2 (MFMA C-input form) into LDS
    {
        const float4* p4 = reinterpret_cast<const float4*>(pnorm);
        float4* d4 = reinterpret_cast<float4*>(s_pn);
        float4 a = p4[tid], b = p4[tid + 256];
        d4[tid]       = make_float4(-.5f*a.x, -.5f*a.y, -.5f*a.z, -.5f*a.w);
        d4[tid + 256] = make_float4(-.5f*b.x, -.5f*b.y, -.5f*b.z, -.5f*b.w);
    }

    int wid   = tid >> 6, lane = tid & 63;
    int m     = lane & 15, q = lane >> 4;
    int pairw = wid >> 1, half = wid & 1;
    int rbase = blockIdx.x * 128 + pairw * 64;

    // A fragments: 4 row-tiles = 64 rows/wave; lane holds A[m][q*32+j].
    AFrag afrag[4];
#pragma unroll
    for (int t = 0; t < 4; ++t) {
        const float* xp = x + (size_t)(rbase + t * 16 + m) * DIMS + q * 32;
        float s = 0.f;
#pragma unroll
        for (int d = 0; d < 8; ++d) {
            float4 v = *reinterpret_cast<const float4*>(xp + d * 4);
            int w0 = __builtin_amdgcn_cvt_pk_fp8_f32(v.x, v.y, 0, false);
            w0 = __builtin_amdgcn_cvt_pk_fp8_f32(v.z, v.w, w0, true);
            afrag[t].d[d] = w0;
            s += v.x * v.x + v.y * v.y + v.z * v.z + v.w * v.w;
        }
        s += __shfl_xor(s, 16, 64);
        s += __shfl_xor(s, 32, 64);
        if (half == 0 && q == 0) s_xn[pairw * 64 + t * 16 + m] = s;
    }
    __syncthreads();   // s_pn + s_xn visible; only barrier before epilogue

    // runmax tracks max_p (x.p - ||p||^2/2); d2 = ||x||^2 - 2*max at the end.
    float runmax[4][4];
#pragma unroll
    for (int t = 0; t < 4; ++t)
#pragma unroll
        for (int r = 0; r < 4; ++r) runmax[t][r] = -1e30f;

    const uint4* bsw = reinterpret_cast<const uint4*>(ptsf8);
    const int T0 = half * 64;      // this wave's 64-tile half of the points

    BFrag bA, bB, bC, bD;
    float pnA, pnB, pnC, pnD;

#define LOADT(gT, buf, pnh) do {                       \
        buf.u4[0] = bsw[(gT) * 128 + lane];            \
        buf.u4[1] = bsw[(gT) * 128 + 64 + lane];       \
        pnh = s_pn[(gT) * 16 + m];                     \
    } while (0)

    auto compute = [&](const BFrag& buf, float pnh) {
#pragma unroll
        for (int t = 0; t < 4; ++t) {
            f32x4 acc = {pnh, pnh, pnh, pnh};   // C = -||p||^2/2 broadcast
            acc = __builtin_amdgcn_mfma_scale_f32_16x16x128_f8f6f4(
                afrag[t].v, buf.v, acc, 0, 0, 0, 0x7F7F7F7F, 0, 0x7F7F7F7F);
#pragma unroll
            for (int r = 0; r < 4; ++r)
                runmax[t][r] = fmaxf(runmax[t][r], acc[r]);
        }
    };

    // depth-4 register prefetch; steady loop branch-free and NOT unrolled
    // (R9 lesson: full unroll -> live-range blowup -> 460 MB spill).
    LOADT(T0 + 0, bA, pnA);
    LOADT(T0 + 1, bB, pnB);
    LOADT(T0 + 2, bC, pnC);
    LOADT(T0 + 3, bD, pnD);
#pragma unroll 1
    for (int T = 0; T < 60; T += 4) {
        compute(bA, pnA);
        LOADT(T0 + T + 4, bA, pnA);
        compute(bB, pnB);
        LOADT(T0 + T + 5, bB, pnB);
        compute(bC, pnC);
        LOADT(T0 + T + 6, bC, pnC);
        compute(bD, pnD);
        LOADT(T0 + T + 7, bD, pnD);
    }
    compute(bA, pnA);
    compute(bB, pnB);
    compute(bC, pnC);
    compute(bD, pnD);
#undef LOADT

    // C/D layout: col = m (point), row_local = q*4 + r (x-row).
    // Max-reduce over the 16 cols, store per-half partial to LDS.
#pragma unroll
    for (int t = 0; t < 4; ++t) {
#pragma unroll
        for (int r = 0; r < 4; ++r) {
            float v = runmax[t][r];
            v = fmaxf(v, __shfl_xor(v, 1, 64));
            v = fmaxf(v, __shfl_xor(v, 2, 64));
            v = fmaxf(v, __shfl_xor(v, 4, 64));
            v = fmaxf(v, __shfl_xor(v, 8, 64));
            if (m == 0)
                s_red[half][pairw * 64 + t * 16 + q * 4 + r] = v;
        }
    }
    __syncthreads();

    if (tid < 128) {
        float vmax  = fmaxf(s_red[0][tid], s_red[1][tid]);
        float d2    = fmaxf(fmaf(-2.f, vmax, s_xn[tid]), 0.f);
        float br    = beta_raw[0];
        float beta  = log1pf(expf(br));
        float alpha = -beta * LOG1000F;
        float z     = (d2 + alpha) / beta;
        out[(size_t)blockIdx.x * 128 + tid] = 1.f / (1.f + expf(-z));
    }
}

extern "C" void kernel_launch(void* const* d_in, const int* in_sizes, int n_in,
                              void* d_out, int out_size, void* d_ws, size_t ws_size,
                              hipStream_t stream) {
    const float* x        = (const float*)d_in[0];
    const float* pts      = (const float*)d_in[1];
    const float* beta_raw = (const float*)d_in[2];
    float* out            = (float*)d_out;

    unsigned char* ptsf8 = (unsigned char*)d_ws;                    // 256 KB
    float* pnorm = (float*)((char*)d_ws + (size_t)NPTS * DIMS);     // 8 KB

    prep_points_kernel<<<NPTS / 4, 256, 0, stream>>>(pts, ptsf8, pnorm);
    // MEASUREMENT: main launched TWICE (idempotent). wall = overhead + 2*m,
    // overhead calibrated at 62+-3 us from R2/R3 -> reads m at +-1.5 us.
    distnet_main_kernel<<<NROWS / 128, 256, 0, stream>>>(x, ptsf8, pnorm,
                                                         beta_raw, out);
    distnet_main_kernel<<<NROWS / 128, 256, 0, stream>>>(x, ptsf8, pnorm,
                                                         beta_raw, out);
}

// Round 7
// 104.495 us; speedup vs baseline: 1.0962x; 1.0962x over previous
//
#include <hip/hip_runtime.h>

// DistNet: out[n] = sigmoid((min_p ||x_n - p||^2 + alpha) / beta)
// beta = softplus(beta_raw), alpha = -beta*ln(1000)
// x: [65536,128] f32, points: [2048,128] f32, beta_raw: [1] f32, out: [65536] f32
//
// R13: R12's double-launch measurement pinned main at ~26 us vs a ~300
// cy/step arithmetic floor -> ~3x latency stalls at 2 waves/SIMD (grid 512
// blocks = 2 blocks/CU caps occupancy; VGPR ~120 would allow 4). R10's
// 4-blocks/CU try failed because 64-row blocks DOUBLED B L2-traffic past
// the per-CU ceiling. R13 runs the clean experiment: 1024 blocks, each =
// 128 rows x ONE point-half (1024 pts) -> B-traffic stays 134 MB, per-wave
// structure is exactly R12's (64-row wave pairs, halves split tiles, depth-4
// named-buffer prefetch, unroll 1), occupancy 4 blocks/CU = 4 waves/SIMD.
// Blocks write per-row partials (xn - 2*vmax_half) to ws; a tiny combine
// kernel does min/clip/sigmoid. Exact: max/min are exact selections.

#define NROWS 65536
#define NPTS  2048
#define DIMS  128
#define LOG1000F 6.9077542789816375f

typedef __attribute__((ext_vector_type(8))) int i32x8;
typedef __attribute__((ext_vector_type(4))) float f32x4;

union AFrag { int d[8]; i32x8 v; };
union BFrag { uint4 u4[2]; i32x8 v; };

// --- pre-kernel: points f32 -> fp8 e4m3, PRE-SWIZZLED fragment order --------
// 16B unit u = (T*2+c)*64 + q*16 + m  holds point p = T*16+m, features
// k in [q*32+c*16, q*32+c*16+16). Main kernel B-load for tile T is then
// unit[(T*2+c)*64 + lane], i.e. two contiguous 1KB dwordx4 loads.
// Also writes ||p||^2.
__global__ __launch_bounds__(256) void prep_points_kernel(
    const float* __restrict__ pts, unsigned char* __restrict__ ptsf8,
    float* __restrict__ pnorm)
{
    int tid  = threadIdx.x;
    int lane = tid & 63;
    int w    = tid >> 6;
    int pt   = blockIdx.x * 4 + w;            // one wave per point
    const float2 v = *reinterpret_cast<const float2*>(
        pts + (size_t)pt * DIMS + lane * 2);  // features 2*lane, 2*lane+1
    int pk = __builtin_amdgcn_cvt_pk_fp8_f32(v.x, v.y, 0, false);
    int T  = pt >> 4, pm = pt & 15;
    int q  = lane >> 4;                       // (2*lane)>>5
    int c  = (lane >> 3) & 1;                 // ((2*lane)>>4)&1
    int j  = (lane & 7) * 2;                  // (2*lane)&15
    size_t dst = (size_t)((T * 2 + c) * 64 + q * 16 + pm) * 16 + j;
    *reinterpret_cast<unsigned short*>(ptsf8 + dst) =
        (unsigned short)(pk & 0xFFFF);
    float ss = v.x * v.x + v.y * v.y;
    ss += __shfl_xor(ss, 1, 64);
    ss += __shfl_xor(ss, 2, 64);
    ss += __shfl_xor(ss, 4, 64);
    ss += __shfl_xor(ss, 8, 64);
    ss += __shfl_xor(ss, 16, 64);
    ss += __shfl_xor(ss, 32, 64);
    if (lane == 0) pnorm[pt] = ss;
}

// --- main kernel ------------------------------------------------------------
// grid: 1024 blocks x 256 threads (4 waves; ~120 VGPR -> 4 blocks/CU =
// 4 waves/SIMD). Block bb: row-group g = bb>>1 (128 rows), point-half
// h = bb&1 (64 tiles). Wave pair owns 64 rows; wave-half splits the 64
// tiles 32 each. Writes partial[h][row] = xn - 2*vmax_half to workspace.
__global__ __launch_bounds__(256, 2) void distnet_main_kernel(
    const float* __restrict__ x, const unsigned char* __restrict__ ptsf8,
    const float* __restrict__ pnorm, float* __restrict__ partial)
{
    __shared__ __align__(16) float s_pn[NPTS / 2];  // 4 KB: this half's -pn/2
    __shared__ float s_red[2][128];                 // per-wavehalf partial max
    __shared__ float s_xn[128];                     // ||x||^2 per block row

    int tid = threadIdx.x;
    int g   = blockIdx.x >> 1;       // row-group (128 rows)
    int h   = blockIdx.x & 1;        // point-half (tiles h*64 .. h*64+63)

    // stage -0.5*||p||^2 for this half: 256 thr x 1 float4 = 1024 floats
    {
        const float4* p4 = reinterpret_cast<const float4*>(pnorm + h * 1024);
        float4 a = p4[tid];
        reinterpret_cast<float4*>(s_pn)[tid] =
            make_float4(-.5f*a.x, -.5f*a.y, -.5f*a.z, -.5f*a.w);
    }

    int wid   = tid >> 6, lane = tid & 63;
    int m     = lane & 15, q = lane >> 4;
    int pairw = wid >> 1, halfw = wid & 1;
    int rbase = g * 128 + pairw * 64;

    // A fragments: 4 row-tiles = 64 rows/wave; lane holds A[m][q*32+j].
    AFrag afrag[4];
#pragma unroll
    for (int t = 0; t < 4; ++t) {
        const float* xp = x + (size_t)(rbase + t * 16 + m) * DIMS + q * 32;
        float s = 0.f;
#pragma unroll
        for (int d = 0; d < 8; ++d) {
            float4 v = *reinterpret_cast<const float4*>(xp + d * 4);
            int w0 = __builtin_amdgcn_cvt_pk_fp8_f32(v.x, v.y, 0, false);
            w0 = __builtin_amdgcn_cvt_pk_fp8_f32(v.z, v.w, w0, true);
            afrag[t].d[d] = w0;
            s += v.x * v.x + v.y * v.y + v.z * v.z + v.w * v.w;
        }
        s += __shfl_xor(s, 16, 64);
        s += __shfl_xor(s, 32, 64);
        if (halfw == 0 && q == 0) s_xn[pairw * 64 + t * 16 + m] = s;
    }
    __syncthreads();   // s_pn + s_xn visible; only barrier before epilogue

    // runmax tracks max_p (x.p - ||p||^2/2) over this wave's 32 tiles.
    float runmax[4][4];
#pragma unroll
    for (int t = 0; t < 4; ++t)
#pragma unroll
        for (int r = 0; r < 4; ++r) runmax[t][r] = -1e30f;

    const uint4* bsw = reinterpret_cast<const uint4*>(ptsf8)
                       + (size_t)h * 64 * 128;    // this half's 64 tiles
    const int T0 = halfw * 32;   // wave's 32-tile quarter (local tile idx)

    BFrag bA, bB, bC, bD;
    float pnA, pnB, pnC, pnD;

#define LOADT(gT, buf, pnh) do {                       \
        buf.u4[0] = bsw[(gT) * 128 + lane];            \
        buf.u4[1] = bsw[(gT) * 128 + 64 + lane];       \
        pnh = s_pn[(gT) * 16 + m];                     \
    } while (0)

    auto compute = [&](const BFrag& buf, float pnh) {
#pragma unroll
        for (int t = 0; t < 4; ++t) {
            f32x4 acc = {pnh, pnh, pnh, pnh};   // C = -||p||^2/2 broadcast
            acc = __builtin_amdgcn_mfma_scale_f32_16x16x128_f8f6f4(
                afrag[t].v, buf.v, acc, 0, 0, 0, 0x7F7F7F7F, 0, 0x7F7F7F7F);
#pragma unroll
            for (int r = 0; r < 4; ++r)
                runmax[t][r] = fmaxf(runmax[t][r], acc[r]);
        }
    };

    // depth-4 register prefetch; steady loop branch-free and NOT unrolled
    // (R9 lesson: full unroll -> live-range blowup -> spill).
    LOADT(T0 + 0, bA, pnA);
    LOADT(T0 + 1, bB, pnB);
    LOADT(T0 + 2, bC, pnC);
    LOADT(T0 + 3, bD, pnD);
#pragma unroll 1
    for (int T = 0; T < 28; T += 4) {
        compute(bA, pnA);
        LOADT(T0 + T + 4, bA, pnA);
        compute(bB, pnB);
        LOADT(T0 + T + 5, bB, pnB);
        compute(bC, pnC);
        LOADT(T0 + T + 6, bC, pnC);
        compute(bD, pnD);
        LOADT(T0 + T + 7, bD, pnD);
    }
    compute(bA, pnA);
    compute(bB, pnB);
    compute(bC, pnC);
    compute(bD, pnD);
#undef LOADT

    // C/D layout: col = m (point), row_local = q*4 + r (x-row).
    // Max-reduce over the 16 cols, store per-wavehalf partial to LDS.
#pragma unroll
    for (int t = 0; t < 4; ++t) {
#pragma unroll
        for (int r = 0; r < 4; ++r) {
            float v = runmax[t][r];
            v = fmaxf(v, __shfl_xor(v, 1, 64));
            v = fmaxf(v, __shfl_xor(v, 2, 64));
            v = fmaxf(v, __shfl_xor(v, 4, 64));
            v = fmaxf(v, __shfl_xor(v, 8, 64));
            if (m == 0)
                s_red[halfw][pairw * 64 + t * 16 + q * 4 + r] = v;
        }
    }
    __syncthreads();

    if (tid < 128) {
        float vmax = fmaxf(s_red[0][tid], s_red[1][tid]);
        // partial[h][row] = ||x||^2 - 2*vmax_half  (no clip; combine does it)
        partial[(size_t)h * NROWS + g * 128 + tid] =
            fmaf(-2.f, vmax, s_xn[tid]);
    }
}

// --- combine kernel ---------------------------------------------------------
// d2 = max(min(p0, p1), 0); out = sigmoid((d2 + alpha)/beta).
// 64 blocks x 256 thr x float4 = 65536.
__global__ __launch_bounds__(256) void distnet_combine_kernel(
    const float* __restrict__ partial, const float* __restrict__ beta_raw,
    float* __restrict__ out)
{
    int i = blockIdx.x * 256 + threadIdx.x;
    float4 p0 = reinterpret_cast<const float4*>(partial)[i];
    float4 p1 = reinterpret_cast<const float4*>(partial + NROWS)[i];
    float br    = beta_raw[0];
    float beta  = log1pf(expf(br));
    float alpha = -beta * LOG1000F;
    float4 o;
    o.x = 1.f / (1.f + expf(-(fmaxf(fminf(p0.x, p1.x), 0.f) + alpha) / beta));
    o.y = 1.f / (1.f + expf(-(fmaxf(fminf(p0.y, p1.y), 0.f) + alpha) / beta));
    o.z = 1.f / (1.f + expf(-(fmaxf(fminf(p0.z, p1.z), 0.f) + alpha) / beta));
    o.w = 1.f / (1.f + expf(-(fmaxf(fminf(p0.w, p1.w), 0.f) + alpha) / beta));
    reinterpret_cast<float4*>(out)[i] = o;
}

extern "C" void kernel_launch(void* const* d_in, const int* in_sizes, int n_in,
                              void* d_out, int out_size, void* d_ws, size_t ws_size,
                              hipStream_t stream) {
    const float* x        = (const float*)d_in[0];
    const float* pts      = (const float*)d_in[1];
    const float* beta_raw = (const float*)d_in[2];
    float* out            = (float*)d_out;

    unsigned char* ptsf8 = (unsigned char*)d_ws;                    // 256 KB
    float* pnorm = (float*)((char*)d_ws + (size_t)NPTS * DIMS);     // 8 KB
    float* partial = (float*)((char*)d_ws + (size_t)NPTS * DIMS
                              + NPTS * sizeof(float));              // 512 KB

    prep_points_kernel<<<NPTS / 4, 256, 0, stream>>>(pts, ptsf8, pnorm);
    distnet_main_kernel<<<NROWS / 64, 256, 0, stream>>>(x, ptsf8, pnorm,
                                                        partial);
    distnet_combine_kernel<<<NROWS / 1024, 256, 0, stream>>>(partial,
                                                             beta_raw, out);
}

// Round 8
// 92.345 us; speedup vs baseline: 1.2404x; 1.1316x over previous
//
#include <hip/hip_runtime.h>

// DistNet: out[n] = sigmoid((min_p ||x_n - p||^2 + alpha) / beta)
// beta = softplus(beta_raw), alpha = -beta*ln(1000)
// x: [65536,128] f32, points: [2048,128] f32, beta_raw: [1] f32, out: [65536] f32
//
// R14: session triangulation (serialized model: wall = gaps 10 + fill 43 +
// prep 4 + main) gives main = 46 (R10/R11), 28.7 (R12, from the 2x-launch
// measurement), 42 (R13). m correlates EXACTLY with x-preamble duplication
// (R12 reads x 2x = 64 MB, all 1024-block variants 4x = 128 MB) -- the
// preamble is the latency-exposed burst phase. R14 = R12's exact topology
// and B-loop (512 blocks x 256 thr, wave pair owns 64 rows, halves split
// the 128 point-tiles, depth-4 named-buffer prefetch, unroll 1), run
// SINGLE-launch, with the preamble deduplicated to 1x (32 MB): each wave
// converts only its own 2 row-tiles and shares fragments + ||x||^2 via LDS
// (16 KB one-time, covered by the existing barrier).

#define NROWS 65536
#define NPTS  2048
#define DIMS  128
#define LOG1000F 6.9077542789816375f

typedef __attribute__((ext_vector_type(8))) int i32x8;
typedef __attribute__((ext_vector_type(4))) float f32x4;

union AFrag { int d[8]; i32x8 v; };
union BFrag { uint4 u4[2]; i32x8 v; };

// --- pre-kernel: points f32 -> fp8 e4m3, PRE-SWIZZLED fragment order --------
// 16B unit u = (T*2+c)*64 + q*16 + m  holds point p = T*16+m, features
// k in [q*32+c*16, q*32+c*16+16). Main kernel B-load for tile T is then
// unit[(T*2+c)*64 + lane], i.e. two contiguous 1KB dwordx4 loads.
// Also writes ||p||^2.
__global__ __launch_bounds__(256) void prep_points_kernel(
    const float* __restrict__ pts, unsigned char* __restrict__ ptsf8,
    float* __restrict__ pnorm)
{
    int tid  = threadIdx.x;
    int lane = tid & 63;
    int w    = tid >> 6;
    int pt   = blockIdx.x * 4 + w;            // one wave per point
    const float2 v = *reinterpret_cast<const float2*>(
        pts + (size_t)pt * DIMS + lane * 2);  // features 2*lane, 2*lane+1
    int pk = __builtin_amdgcn_cvt_pk_fp8_f32(v.x, v.y, 0, false);
    int T  = pt >> 4, pm = pt & 15;
    int q  = lane >> 4;                       // (2*lane)>>5
    int c  = (lane >> 3) & 1;                 // ((2*lane)>>4)&1
    int j  = (lane & 7) * 2;                  // (2*lane)&15
    size_t dst = (size_t)((T * 2 + c) * 64 + q * 16 + pm) * 16 + j;
    *reinterpret_cast<unsigned short*>(ptsf8 + dst) =
        (unsigned short)(pk & 0xFFFF);
    float ss = v.x * v.x + v.y * v.y;
    ss += __shfl_xor(ss, 1, 64);
    ss += __shfl_xor(ss, 2, 64);
    ss += __shfl_xor(ss, 4, 64);
    ss += __shfl_xor(ss, 8, 64);
    ss += __shfl_xor(ss, 16, 64);
    ss += __shfl_xor(ss, 32, 64);
    if (lane == 0) pnorm[pt] = ss;
}

// --- main kernel ------------------------------------------------------------
// grid: NROWS/128 = 512 blocks x 256 threads (4 waves, 2 per CU).
// Preamble: wave w converts row-tiles {2w, 2w+1} (its unique 32 rows ->
// x read exactly once), publishes fragments via LDS. Main loop: wave pair
// (pairw) owns 64 rows (tiles pairw*4..pairw*4+3); half=0 wave does
// point-tiles 0..63, half=1 does 64..127. No barriers in the main loop.
__global__ __launch_bounds__(256, 2) void distnet_main_kernel(
    const float* __restrict__ x, const unsigned char* __restrict__ ptsf8,
    const float* __restrict__ pnorm, const float* __restrict__ beta_raw,
    float* __restrict__ out)
{
    __shared__ __align__(16) float s_pn[NPTS];   // 8 KB: -0.5*||p||^2
    __shared__ __align__(16) int s_af[8][64][8]; // 16 KB: A-frags, 8 row-tiles
    __shared__ float s_red[2][128];              // per-half partial max
    __shared__ float s_xn[128];                  // ||x||^2 per block row

    int tid = threadIdx.x;
    // stage -0.5*||p||^2 (MFMA C-input form) into LDS
    {
        const float4* p4 = reinterpret_cast<const float4*>(pnorm);
        float4* d4 = reinterpret_cast<float4*>(s_pn);
        float4 a = p4[tid], b = p4[tid + 256];
        d4[tid]       = make_float4(-.5f*a.x, -.5f*a.y, -.5f*a.z, -.5f*a.w);
        d4[tid + 256] = make_float4(-.5f*b.x, -.5f*b.y, -.5f*b.z, -.5f*b.w);
    }

    int wid   = tid >> 6, lane = tid & 63;
    int m     = lane & 15, q = lane >> 4;
    int pairw = wid >> 1, half = wid & 1;
    int rbase0 = blockIdx.x * 128;

    // Preamble: wave wid converts row-tiles {2*wid, 2*wid+1} only (x 1x).
    // Lane holds A[m][q*32+j] of each tile; publish to LDS for all waves.
#pragma unroll
    for (int i = 0; i < 2; ++i) {
        int lt = wid * 2 + i;                       // row-tile 0..7 in block
        const float* xp = x + (size_t)(rbase0 + lt * 16 + m) * DIMS + q * 32;
        AFrag af;
        float s = 0.f;
#pragma unroll
        for (int d = 0; d < 8; ++d) {
            float4 v = *reinterpret_cast<const float4*>(xp + d * 4);
            int w0 = __builtin_amdgcn_cvt_pk_fp8_f32(v.x, v.y, 0, false);
            w0 = __builtin_amdgcn_cvt_pk_fp8_f32(v.z, v.w, w0, true);
            af.d[d] = w0;
            s += v.x * v.x + v.y * v.y + v.z * v.z + v.w * v.w;
        }
        s += __shfl_xor(s, 16, 64);
        s += __shfl_xor(s, 32, 64);
        if (q == 0) s_xn[lt * 16 + m] = s;          // rows lt*16 + 0..15
        *reinterpret_cast<i32x8*>(&s_af[lt][lane][0]) = af.v;
    }
    __syncthreads();   // s_pn + s_xn + s_af visible; only barrier before epi

    // Read back this wave's 4 row-tiles (pair's 64 rows) from LDS.
    AFrag afrag[4];
#pragma unroll
    for (int t = 0; t < 4; ++t)
        afrag[t].v = *reinterpret_cast<const i32x8*>(&s_af[pairw * 4 + t][lane][0]);

    // runmax tracks max_p (x.p - ||p||^2/2); d2 = ||x||^2 - 2*max at the end.
    float runmax[4][4];
#pragma unroll
    for (int t = 0; t < 4; ++t)
#pragma unroll
        for (int r = 0; r < 4; ++r) runmax[t][r] = -1e30f;

    const uint4* bsw = reinterpret_cast<const uint4*>(ptsf8);
    const int T0 = half * 64;      // this wave's 64-tile half of the points

    BFrag bA, bB, bC, bD;
    float pnA, pnB, pnC, pnD;

#define LOADT(gT, buf, pnh) do {                       \
        buf.u4[0] = bsw[(gT) * 128 + lane];            \
        buf.u4[1] = bsw[(gT) * 128 + 64 + lane];       \
        pnh = s_pn[(gT) * 16 + m];                     \
    } while (0)

    auto compute = [&](const BFrag& buf, float pnh) {
#pragma unroll
        for (int t = 0; t < 4; ++t) {
            f32x4 acc = {pnh, pnh, pnh, pnh};   // C = -||p||^2/2 broadcast
            acc = __builtin_amdgcn_mfma_scale_f32_16x16x128_f8f6f4(
                afrag[t].v, buf.v, acc, 0, 0, 0, 0x7F7F7F7F, 0, 0x7F7F7F7F);
#pragma unroll
            for (int r = 0; r < 4; ++r)
                runmax[t][r] = fmaxf(runmax[t][r], acc[r]);
        }
    };

    // depth-4 register prefetch; steady loop branch-free and NOT unrolled
    // (R9 lesson: full unroll -> live-range blowup -> spill).
    LOADT(T0 + 0, bA, pnA);
    LOADT(T0 + 1, bB, pnB);
    LOADT(T0 + 2, bC, pnC);
    LOADT(T0 + 3, bD, pnD);
#pragma unroll 1
    for (int T = 0; T < 60; T += 4) {
        compute(bA, pnA);
        LOADT(T0 + T + 4, bA, pnA);
        compute(bB, pnB);
        LOADT(T0 + T + 5, bB, pnB);
        compute(bC, pnC);
        LOADT(T0 + T + 6, bC, pnC);
        compute(bD, pnD);
        LOADT(T0 + T + 7, bD, pnD);
    }
    compute(bA, pnA);
    compute(bB, pnB);
    compute(bC, pnC);
    compute(bD, pnD);
#undef LOADT

    // C/D layout: col = m (point), row_local = q*4 + r (x-row).
    // Max-reduce over the 16 cols, store per-half partial to LDS.
#pragma unroll
    for (int t = 0; t < 4; ++t) {
#pragma unroll
        for (int r = 0; r < 4; ++r) {
            float v = runmax[t][r];
            v = fmaxf(v, __shfl_xor(v, 1, 64));
            v = fmaxf(v, __shfl_xor(v, 2, 64));
            v = fmaxf(v, __shfl_xor(v, 4, 64));
            v = fmaxf(v, __shfl_xor(v, 8, 64));
            if (m == 0)
                s_red[half][pairw * 64 + t * 16 + q * 4 + r] = v;
        }
    }
    __syncthreads();

    if (tid < 128) {
        float vmax  = fmaxf(s_red[0][tid], s_red[1][tid]);
        float d2    = fmaxf(fmaf(-2.f, vmax, s_xn[tid]), 0.f);
        float br    = beta_raw[0];
        float beta  = log1pf(expf(br));
        float alpha = -beta * LOG1000F;
        float z     = (d2 + alpha) / beta;
        out[(size_t)blockIdx.x * 128 + tid] = 1.f / (1.f + expf(-z));
    }
}

extern "C" void kernel_launch(void* const* d_in, const int* in_sizes, int n_in,
                              void* d_out, int out_size, void* d_ws, size_t ws_size,
                              hipStream_t stream) {
    const float* x        = (const float*)d_in[0];
    const float* pts      = (const float*)d_in[1];
    const float* beta_raw = (const float*)d_in[2];
    float* out            = (float*)d_out;

    unsigned char* ptsf8 = (unsigned char*)d_ws;                    // 256 KB
    float* pnorm = (float*)((char*)d_ws + (size_t)NPTS * DIMS);     // 8 KB

    prep_points_kernel<<<NPTS / 4, 256, 0, stream>>>(pts, ptsf8, pnorm);
    distnet_main_kernel<<<NROWS / 128, 256, 0, stream>>>(x, ptsf8, pnorm,
                                                         beta_raw, out);
}